// Round 9
// baseline (373.721 us; speedup 1.0000x reference)
//
#include <hip/hip_runtime.h>

#define N_NODES 50000
#define N_EDGES 800000
#define EP (N_EDGES + N_NODES)   /* 850000 edges incl. self loops */
#define HEADS 8
#define NEG 0.2f

typedef __attribute__((ext_vector_type(8))) short bf16x8;
typedef __attribute__((ext_vector_type(8))) unsigned short u16x8;
typedef __attribute__((ext_vector_type(4))) float f32x4;

// ---- bf16 helpers (storage compression; math stays fp32) ----------------

__device__ __forceinline__ float bf2f(unsigned short u) {
    return __uint_as_float(((unsigned)u) << 16);
}
__device__ __forceinline__ unsigned short f2bf(float f) {
    unsigned u = __float_as_uint(f);
    return (unsigned short)((u + 0x7FFFu + ((u >> 16) & 1u)) >> 16);  // RNE
}

__device__ __forceinline__ void get_edge(const int* __restrict__ ei, int e, int& s, int& d) {
    if (e < N_EDGES) { s = ei[e]; d = ei[N_EDGES + e]; }
    else             { s = d = e - N_EDGES; }           // self loop
}

__device__ __forceinline__ float lrelu(float v) { return v > 0.f ? v : NEG * v; }

// ---- hist + W-transpose (fused, independent work ranges) ----------------

#define E_BLOCKS ((EP + 255) / 256)        /* 3321 */
#define W_ITEMS  (65536 + 32768)
#define W_BLOCKS ((W_ITEMS + 255) / 256)   /* 384 */

__global__ void hist_prep(const int* __restrict__ ei, int* __restrict__ cnt,
                          const float* __restrict__ W1, const float* __restrict__ W2,
                          unsigned short* __restrict__ W1T, unsigned short* __restrict__ W2T) {
    const int b = blockIdx.x;
    if (b < E_BLOCKS) {
        int e = b * 256 + threadIdx.x;
        if (e >= EP) return;
        int s, d; get_edge(ei, e, s, d);
        atomicAdd(&cnt[d], 1);
    } else {
        int t = (b - E_BLOCKS) * 256 + threadIdx.x;
        if (t < 65536) {
            int k = t >> 8, n = t & 255;
            W1T[n * 256 + k] = f2bf(W1[k * 256 + n]);
        } else if (t < W_ITEMS) {
            int u = t - 65536; int k = u >> 7, n = u & 127;
            W2T[n * 256 + k] = f2bf(W2[k * 128 + n]);
        }
    }
}

// ---- 3-phase parallel exclusive scan ------------------------------------

#define SCAN_BLOCKS 196   /* 196*256 = 50176 >= N_NODES */

__global__ __launch_bounds__(256) void scan_p1(const int* __restrict__ cnt,
                                               int* __restrict__ incl, int* __restrict__ bsum) {
    __shared__ int wsum[4];
    const int tid = threadIdx.x, lane = tid & 63, wid = tid >> 6;
    const int idx = blockIdx.x * 256 + tid;
    int v = (idx < N_NODES) ? cnt[idx] : 0;
#pragma unroll
    for (int off = 1; off < 64; off <<= 1) {
        int t = __shfl_up(v, off);
        if (lane >= off) v += t;
    }
    if (lane == 63) wsum[wid] = v;
    __syncthreads();
    int add = 0;
#pragma unroll
    for (int w = 0; w < 4; w++) add += (w < wid) ? wsum[w] : 0;
    incl[idx] = v + add;
    if (tid == 255) bsum[blockIdx.x] = v + add;
}

__global__ __launch_bounds__(256) void scan_p2(const int* __restrict__ bsum,
                                               int* __restrict__ bex) {
    __shared__ int wsum[4];
    const int tid = threadIdx.x, lane = tid & 63, wid = tid >> 6;
    int v0 = (tid < SCAN_BLOCKS) ? bsum[tid] : 0;
    int v = v0;
#pragma unroll
    for (int off = 1; off < 64; off <<= 1) {
        int t = __shfl_up(v, off);
        if (lane >= off) v += t;
    }
    if (lane == 63) wsum[wid] = v;
    __syncthreads();
    int add = 0;
#pragma unroll
    for (int w = 0; w < 4; w++) add += (w < wid) ? wsum[w] : 0;
    if (tid < SCAN_BLOCKS) bex[tid] = v + add - v0;
}

__global__ __launch_bounds__(256) void scan_p3(const int* __restrict__ incl,
                                               const int* __restrict__ bex,
                                               int* __restrict__ cnt_cursor,
                                               int* __restrict__ row_start) {
    const int idx = blockIdx.x * 256 + threadIdx.x;
    if (idx == 0) row_start[N_NODES] = EP;
    if (idx >= N_NODES) return;
    int ex = bex[blockIdx.x] + incl[idx] - cnt_cursor[idx];
    row_start[idx] = ex;
    cnt_cursor[idx] = ex;
}

__global__ void fill_kernel(const int* __restrict__ ei, int* __restrict__ cursor,
                            unsigned short* __restrict__ csr) {
    int e = blockIdx.x * 256 + threadIdx.x;
    if (e >= EP) return;
    int s, d; get_edge(ei, e, s, d);
    int pos = atomicAdd(&cursor[d], 1);
    csr[pos] = (unsigned short)s;
}

// ---- MFMA GEMM, A read ONCE (BM=64 x full-N) + fused attention epilogue -

template<int NC, int C, bool AF32>
__global__ __launch_bounds__(256) void gemm_fused(const void* __restrict__ Aptr,
        const unsigned short* __restrict__ WT,
        const float* __restrict__ att_s, const float* __restrict__ att_d,
        unsigned short* __restrict__ outh,
        float* __restrict__ a_src, float* __restrict__ a_dst) {
    constexpr int WN  = NC / 4;
    constexpr int NT  = WN / 16;
    constexpr int TPH = C / 16;
    constexpr int BJ  = NC / 32;
    __shared__ unsigned short As[64 * 64];
    __shared__ unsigned short Bs[NC * 64];
    const int m0 = blockIdx.x * 64;
    const int tid  = threadIdx.x;
    const int wave = tid >> 6, lane = tid & 63;
    const int col = lane & 15, quad = lane >> 4;
    const int ar = tid >> 2;
    const int ac = tid & 3;
    const int arow = min(m0 + ar, N_NODES - 1);   // guard input read

    f32x4 acc[4][NT] = {};

    for (int k0 = 0; k0 < 256; k0 += 64) {
        u16x8 av[2];
        if constexpr (AF32) {
            const float* Af = (const float*)Aptr;
#pragma unroll
            for (int j = 0; j < 2; j++) {
                const float* p = Af + (size_t)arow * 256 + k0 + (ac + j * 4) * 8;
                float4 f0 = *(const float4*)p;
                float4 f1 = *(const float4*)(p + 4);
                u16x8 v;
                v[0] = f2bf(f0.x); v[1] = f2bf(f0.y); v[2] = f2bf(f0.z); v[3] = f2bf(f0.w);
                v[4] = f2bf(f1.x); v[5] = f2bf(f1.y); v[6] = f2bf(f1.z); v[7] = f2bf(f1.w);
                av[j] = v;
            }
        } else {
            const unsigned short* Ab = (const unsigned short*)Aptr;
#pragma unroll
            for (int j = 0; j < 2; j++)
                av[j] = *(const u16x8*)(Ab + (size_t)arow * 256 + k0 + (ac + j * 4) * 8);
        }
        u16x8 bv[BJ];
#pragma unroll
        for (int j = 0; j < BJ; j++) {
            int idx = j * 256 + tid, row = idx >> 3, ch = idx & 7;
            bv[j] = *(const u16x8*)(WT + (size_t)row * 256 + k0 + ch * 8);
        }
        __syncthreads();
#pragma unroll
        for (int j = 0; j < 2; j++) {
            int ch = ac + j * 4;
            *(u16x8*)&As[ar * 64 + (ch ^ (ar & 7)) * 8] = av[j];
        }
#pragma unroll
        for (int j = 0; j < BJ; j++) {
            int idx = j * 256 + tid, row = idx >> 3, ch = idx & 7;
            *(u16x8*)&Bs[row * 64 + (ch ^ (row & 7)) * 8] = bv[j];
        }
        __syncthreads();
#pragma unroll
        for (int ks = 0; ks < 64; ks += 32) {
            bf16x8 af[4], bfm[NT];
#pragma unroll
            for (int mi = 0; mi < 4; mi++) {
                int r = mi * 16 + col, c = (ks >> 3) + quad;
                af[mi] = *(const bf16x8*)&As[r * 64 + (c ^ (r & 7)) * 8];
            }
#pragma unroll
            for (int ni = 0; ni < NT; ni++) {
                int r = wave * WN + ni * 16 + col, c = (ks >> 3) + quad;
                bfm[ni] = *(const bf16x8*)&Bs[r * 64 + (c ^ (r & 7)) * 8];
            }
#pragma unroll
            for (int mi = 0; mi < 4; mi++)
#pragma unroll
                for (int ni = 0; ni < NT; ni++)
                    acc[mi][ni] = __builtin_amdgcn_mfma_f32_16x16x32_bf16(
                        af[mi], bfm[ni], acc[mi][ni], 0, 0, 0);
        }
    }

#pragma unroll
    for (int mi = 0; mi < 4; mi++)
#pragma unroll
        for (int ni = 0; ni < NT; ni++)
#pragma unroll
            for (int r = 0; r < 4; r++) {
                int m = m0 + mi * 16 + quad * 4 + r;
                if (m < N_NODES)
                    outh[(size_t)m * NC + wave * WN + ni * 16 + col] = f2bf(acc[mi][ni][r]);
            }

    float asv[NT], adv[NT];
#pragma unroll
    for (int ni = 0; ni < NT; ni++) {
        int n = wave * WN + ni * 16 + col;
        asv[ni] = att_s[n];
        adv[ni] = att_d[n];
    }
#pragma unroll
    for (int mi = 0; mi < 4; mi++)
#pragma unroll
        for (int r = 0; r < 4; r++) {
#pragma unroll
            for (int hl = 0; hl < 2; hl++) {
                float s = 0.f, d = 0.f;
#pragma unroll
                for (int t = 0; t < TPH; t++) {
                    int ni = hl * TPH + t;
                    s = fmaf(acc[mi][ni][r], asv[ni], s);
                    d = fmaf(acc[mi][ni][r], adv[ni], d);
                }
#pragma unroll
                for (int off = 1; off < 16; off <<= 1) {
                    s += __shfl_xor(s, off);
                    d += __shfl_xor(d, off);
                }
                if (col == 0) {
                    int m = m0 + mi * 16 + quad * 4 + r;
                    if (m < N_NODES) {
                        int hh = wave * 2 + hl;
                        a_src[m * 8 + hh] = s;
                        a_dst[m * 8 + hh] = d;
                    }
                }
            }
        }
}

// ---- layer-1 aggregation: ONE WAVE per node, half-wave edge pairing -----
// Half-wave p = lane>>5 handles edge parity p; lane q = lane&31 covers
// feats [q*8,q*8+8) of head q>>2 (16 B dwordx4 gather; 32 lanes = 512 B).
// 16 edges per iteration -> 8 row-gathers + 8 a_src loads in flight per
// half-wave (MLP). No max-subtraction (|e| small -> exp safe in fp32).

__global__ __launch_bounds__(256) void gat_agg_l1(const int* __restrict__ row_start,
        const unsigned short* __restrict__ csr,
        const unsigned short* __restrict__ hfeat, const float* __restrict__ a_src,
        const float* __restrict__ a_dst, const float* __restrict__ bias,
        unsigned short* __restrict__ outp) {
    const int n    = blockIdx.x * 4 + (threadIdx.x >> 6);
    const int lane = threadIdx.x & 63;
    if (n >= N_NODES) return;

    const int rs  = row_start[n];
    const int deg = row_start[n + 1] - rs;
    const int p   = lane >> 5;          // edge parity
    const int q   = lane & 31;          // feat group
    const int hq  = q >> 2;             // head
    const float adstf = a_dst[n * 8 + hq];

    float acc[8] = {};
    float den = 0.f;

    for (int c0 = 0; c0 < deg; c0 += 64) {
        const int cnt = min(64, deg - c0);
        int myid = (lane < cnt) ? (int)csr[rs + c0 + lane] : 0;
        int e = 0;
        for (; e + 16 <= cnt; e += 16) {        // 8 pairs = 16 edges
            int ss[8];
#pragma unroll
            for (int j = 0; j < 8; j++) ss[j] = __shfl(myid, e + j * 2 + p);
            float as[8];
#pragma unroll
            for (int j = 0; j < 8; j++) as[j] = a_src[ss[j] * 8 + hq];
            u16x8 v[8];
#pragma unroll
            for (int j = 0; j < 8; j++)
                v[j] = *(const u16x8*)(hfeat + (size_t)ss[j] * 256 + q * 8);
#pragma unroll
            for (int j = 0; j < 8; j++) {
                float w = __expf(lrelu(as[j] + adstf));
                den += w;
#pragma unroll
                for (int k = 0; k < 8; k++)
                    acc[k] = fmaf(w, bf2f(v[j][k]), acc[k]);
            }
        }
        for (; e < cnt; e += 2) {               // tail pairs
            int idx = e + p;
            bool ok = idx < cnt;
            int s = __shfl(myid, ok ? idx : cnt - 1);
            float w = ok ? __expf(lrelu(a_src[s * 8 + hq] + adstf)) : 0.f;
            den += w;
            u16x8 v = *(const u16x8*)(hfeat + (size_t)s * 256 + q * 8);
#pragma unroll
            for (int k = 0; k < 8; k++)
                acc[k] = fmaf(w, bf2f(v[k]), acc[k]);
        }
    }

    // combine parities
    den += __shfl_xor(den, 32);
#pragma unroll
    for (int k = 0; k < 8; k++) acc[k] += __shfl_xor(acc[k], 32);

    if (p == 0) {
        const float inv = 1.f / (den + 1e-16f);
        float4 b0 = *(const float4*)(bias + q * 8);
        float4 b1 = *(const float4*)(bias + q * 8 + 4);
        float bb[8] = {b0.x, b0.y, b0.z, b0.w, b1.x, b1.y, b1.z, b1.w};
        u16x8 o;
#pragma unroll
        for (int k = 0; k < 8; k++) {
            float v = acc[k] * inv + bb[k];
            o[k] = f2bf(v > 0.f ? v : __expf(v) - 1.f);   // elu
        }
        *(u16x8*)(outp + (size_t)n * 256 + q * 8) = o;
    }
}

// ---- layer-2 aggregation: ONE WAVE per node, half-wave pairing, F=128 ---
// Lane q covers feats [q*4,q*4+4) of head q>>2 (8 B ushort4; 32 lanes =
// 256 B row). 16 edges per iteration. Epilogue: normalize per head, then
// head-mean via xor-shuffles (4,8,16); lanes 0..3 write float4.

__global__ __launch_bounds__(256) void gat_agg_l2(const int* __restrict__ row_start,
        const unsigned short* __restrict__ csr,
        const unsigned short* __restrict__ hfeat, const float* __restrict__ a_src,
        const float* __restrict__ a_dst, const float* __restrict__ bias,
        float* __restrict__ outp) {
    const int n    = blockIdx.x * 4 + (threadIdx.x >> 6);
    const int lane = threadIdx.x & 63;
    if (n >= N_NODES) return;

    const int rs  = row_start[n];
    const int deg = row_start[n + 1] - rs;
    const int p   = lane >> 5;
    const int q   = lane & 31;
    const int hq  = q >> 2;
    const float adstf = a_dst[n * 8 + hq];

    float acc[4] = {};
    float den = 0.f;

    for (int c0 = 0; c0 < deg; c0 += 64) {
        const int cnt = min(64, deg - c0);
        int myid = (lane < cnt) ? (int)csr[rs + c0 + lane] : 0;
        int e = 0;
        for (; e + 16 <= cnt; e += 16) {
            int ss[8];
#pragma unroll
            for (int j = 0; j < 8; j++) ss[j] = __shfl(myid, e + j * 2 + p);
            float as[8];
#pragma unroll
            for (int j = 0; j < 8; j++) as[j] = a_src[ss[j] * 8 + hq];
            ushort4 v[8];
#pragma unroll
            for (int j = 0; j < 8; j++)
                v[j] = *(const ushort4*)(hfeat + (size_t)ss[j] * 128 + q * 4);
#pragma unroll
            for (int j = 0; j < 8; j++) {
                float w = __expf(lrelu(as[j] + adstf));
                den += w;
                acc[0] = fmaf(w, bf2f(v[j].x), acc[0]);
                acc[1] = fmaf(w, bf2f(v[j].y), acc[1]);
                acc[2] = fmaf(w, bf2f(v[j].z), acc[2]);
                acc[3] = fmaf(w, bf2f(v[j].w), acc[3]);
            }
        }
        for (; e < cnt; e += 2) {
            int idx = e + p;
            bool ok = idx < cnt;
            int s = __shfl(myid, ok ? idx : cnt - 1);
            float w = ok ? __expf(lrelu(a_src[s * 8 + hq] + adstf)) : 0.f;
            den += w;
            ushort4 v = *(const ushort4*)(hfeat + (size_t)s * 128 + q * 4);
            acc[0] = fmaf(w, bf2f(v.x), acc[0]);
            acc[1] = fmaf(w, bf2f(v.y), acc[1]);
            acc[2] = fmaf(w, bf2f(v.z), acc[2]);
            acc[3] = fmaf(w, bf2f(v.w), acc[3]);
        }
    }

    // combine parities, normalize per head, then mean over heads
    den += __shfl_xor(den, 32);
#pragma unroll
    for (int k = 0; k < 4; k++) acc[k] += __shfl_xor(acc[k], 32);
    const float inv = 1.f / (den + 1e-16f);
#pragma unroll
    for (int k = 0; k < 4; k++) {
        acc[k] *= inv;
#pragma unroll
        for (int off = 4; off <= 16; off <<= 1)
            acc[k] += __shfl_xor(acc[k], off);   // sum across 8 heads
    }
    if (p == 0 && q < 4) {
        float4 o;
        o.x = acc[0] * 0.125f + bias[q * 4 + 0];
        o.y = acc[1] * 0.125f + bias[q * 4 + 1];
        o.z = acc[2] * 0.125f + bias[q * 4 + 2];
        o.w = acc[3] * 0.125f + bias[q * 4 + 3];
        *(float4*)(outp + (size_t)n * 16 + q * 4) = o;
    }
}

// ---- host ---------------------------------------------------------------

extern "C" void kernel_launch(void* const* d_in, const int* in_sizes, int n_in,
                              void* d_out, int out_size, void* d_ws, size_t ws_size,
                              hipStream_t stream) {
    const float* x        = (const float*)d_in[0];
    const int*   ei       = (const int*)d_in[1];
    const float* W1       = (const float*)d_in[2];
    const float* att_src1 = (const float*)d_in[3];
    const float* att_dst1 = (const float*)d_in[4];
    const float* bias1    = (const float*)d_in[5];
    const float* W2       = (const float*)d_in[6];
    const float* att_src2 = (const float*)d_in[7];
    const float* att_dst2 = (const float*)d_in[8];
    const float* bias2    = (const float*)d_in[9];
    float* out = (float*)d_out;

    char* ws = (char*)d_ws;
    unsigned short* h1  = (unsigned short*)(ws);                       // bf16 [N,256]
    unsigned short* h2  = (unsigned short*)(ws);                       // bf16 [N,128] overlays
    unsigned short* x2b = (unsigned short*)(ws + 32ull * 1024 * 1024); // bf16 [N,256]
    unsigned short* W1T = (unsigned short*)(ws + 64ull * 1024 * 1024); // bf16 [256,256]
    unsigned short* W2T = W1T + 65536;                                 // bf16 [128,256]
    char* aux = ws + 66ull * 1024 * 1024;
    float*          a_src     = (float*)(aux);                         // [N,8]
    float*          a_dst     = (float*)(aux + 1600000);               // [N,8]
    int*            row_start = (int*)  (aux + 3200000);               // [N+1]
    int*            cnt       = (int*)  (aux + 3400064);               // [N] -> cursor
    unsigned short* csr       = (unsigned short*)(aux + 3600128);      // [EP]
    int*            incl      = (int*)  (aux + 5300128);               // [50176]
    int*            bsum      = (int*)  (aux + 5500832);               // [196]
    int*            bex       = (int*)  (aux + 5501632);               // [196]

    const int MT = (N_NODES + 63) / 64;            // 782
    const int AGG_BLOCKS = (N_NODES + 3) / 4;

    // ---- CSR build + W prep ----
    hipMemsetAsync(cnt, 0, N_NODES * sizeof(int), stream);
    hist_prep<<<E_BLOCKS + W_BLOCKS, 256, 0, stream>>>(ei, cnt, W1, W2, W1T, W2T);
    scan_p1<<<SCAN_BLOCKS, 256, 0, stream>>>(cnt, incl, bsum);
    scan_p2<<<1, 256, 0, stream>>>(bsum, bex);
    scan_p3<<<SCAN_BLOCKS, 256, 0, stream>>>(incl, bex, cnt, row_start);
    fill_kernel<<<E_BLOCKS, 256, 0, stream>>>(ei, cnt, csr);

    // ---- layer 1 (GEMM reads fp32 x directly) ----
    gemm_fused<256, 32, true><<<MT, 256, 0, stream>>>(x, W1T, att_src1, att_dst1, h1, a_src, a_dst);
    gat_agg_l1<<<AGG_BLOCKS, 256, 0, stream>>>(row_start, csr, h1, a_src, a_dst, bias1, x2b);

    // ---- layer 2 ----
    gemm_fused<128, 16, false><<<MT, 256, 0, stream>>>(x2b, W2T, att_src2, att_dst2, h2, a_src, a_dst);
    gat_agg_l2<<<AGG_BLOCKS, 256, 0, stream>>>(row_start, csr, h2, a_src, a_dst, bias2, out);
}

// Round 10
// 337.794 us; speedup vs baseline: 1.1064x; 1.1064x over previous
//
#include <hip/hip_runtime.h>

#define N_NODES 50000
#define N_EDGES 800000
#define EP (N_EDGES + N_NODES)   /* 850000 edges incl. self loops */
#define HEADS 8
#define NEG 0.2f

typedef __attribute__((ext_vector_type(8))) short bf16x8;
typedef __attribute__((ext_vector_type(8))) unsigned short u16x8;
typedef __attribute__((ext_vector_type(4))) float f32x4;

// ---- bf16 helpers (storage compression; math stays fp32) ----------------

__device__ __forceinline__ float bf2f(unsigned short u) {
    return __uint_as_float(((unsigned)u) << 16);
}
__device__ __forceinline__ unsigned short f2bf(float f) {
    unsigned u = __float_as_uint(f);
    return (unsigned short)((u + 0x7FFFu + ((u >> 16) & 1u)) >> 16);  // RNE
}

__device__ __forceinline__ void get_edge(const int* __restrict__ ei, int e, int& s, int& d) {
    if (e < N_EDGES) { s = ei[e]; d = ei[N_EDGES + e]; }
    else             { s = d = e - N_EDGES; }           // self loop
}

__device__ __forceinline__ float lrelu(float v) { return v > 0.f ? v : NEG * v; }

// ---- hist + W-transpose (fused, independent work ranges) ----------------

#define E_BLOCKS ((EP + 255) / 256)        /* 3321 */
#define W_ITEMS  (65536 + 32768)
#define W_BLOCKS ((W_ITEMS + 255) / 256)   /* 384 */

__global__ void hist_prep(const int* __restrict__ ei, int* __restrict__ cnt,
                          const float* __restrict__ W1, const float* __restrict__ W2,
                          unsigned short* __restrict__ W1T, unsigned short* __restrict__ W2T) {
    const int b = blockIdx.x;
    if (b < E_BLOCKS) {
        int e = b * 256 + threadIdx.x;
        if (e >= EP) return;
        int s, d; get_edge(ei, e, s, d);
        atomicAdd(&cnt[d], 1);
    } else {
        int t = (b - E_BLOCKS) * 256 + threadIdx.x;
        if (t < 65536) {
            int k = t >> 8, n = t & 255;
            W1T[n * 256 + k] = f2bf(W1[k * 256 + n]);
        } else if (t < W_ITEMS) {
            int u = t - 65536; int k = u >> 7, n = u & 127;
            W2T[n * 256 + k] = f2bf(W2[k * 128 + n]);
        }
    }
}

// ---- 2-phase parallel exclusive scan (block scan + redundant top scan) --

#define SCAN_BLOCKS 196   /* 196*256 = 50176 >= N_NODES */

__global__ __launch_bounds__(256) void scan_p1(const int* __restrict__ cnt,
                                               int* __restrict__ incl, int* __restrict__ bsum) {
    __shared__ int wsum[4];
    const int tid = threadIdx.x, lane = tid & 63, wid = tid >> 6;
    const int idx = blockIdx.x * 256 + tid;
    int v = (idx < N_NODES) ? cnt[idx] : 0;
#pragma unroll
    for (int off = 1; off < 64; off <<= 1) {
        int t = __shfl_up(v, off);
        if (lane >= off) v += t;
    }
    if (lane == 63) wsum[wid] = v;
    __syncthreads();
    int add = 0;
#pragma unroll
    for (int w = 0; w < 4; w++) add += (w < wid) ? wsum[w] : 0;
    incl[idx] = v + add;
    if (tid == 255) bsum[blockIdx.x] = v + add;
}

// each block redundantly scans the 196 block sums, then finalizes its range
__global__ __launch_bounds__(256) void scan_p23(const int* __restrict__ incl,
                                                const int* __restrict__ bsum,
                                                int* __restrict__ cnt_cursor,
                                                int* __restrict__ row_start) {
    __shared__ int sb[256];
    __shared__ int wsum[4];
    const int tid = threadIdx.x, lane = tid & 63, wid = tid >> 6;
    int v = (tid < SCAN_BLOCKS) ? bsum[tid] : 0;
#pragma unroll
    for (int off = 1; off < 64; off <<= 1) {
        int t = __shfl_up(v, off);
        if (lane >= off) v += t;
    }
    if (lane == 63) wsum[wid] = v;
    __syncthreads();
    int add = 0;
#pragma unroll
    for (int w = 0; w < 4; w++) add += (w < wid) ? wsum[w] : 0;
    sb[tid] = v + add;                     // inclusive scan of bsum
    __syncthreads();
    const int bex = (blockIdx.x == 0) ? 0 : sb[blockIdx.x - 1];
    const int idx = blockIdx.x * 256 + tid;
    if (idx == 0) row_start[N_NODES] = EP;
    if (idx >= N_NODES) return;
    int ex = bex + incl[idx] - cnt_cursor[idx];   // within-block exclusive + carry
    row_start[idx] = ex;
    cnt_cursor[idx] = ex;
}

__global__ void fill_kernel(const int* __restrict__ ei, int* __restrict__ cursor,
                            unsigned short* __restrict__ csr) {
    int e = blockIdx.x * 256 + threadIdx.x;
    if (e >= EP) return;
    int s, d; get_edge(ei, e, s, d);
    int pos = atomicAdd(&cursor[d], 1);
    csr[pos] = (unsigned short)s;
}

// ---- MFMA GEMM, A read ONCE (BM=64 x full-N) + fused attention epilogue -

template<int NC, int C, bool AF32>
__global__ __launch_bounds__(256) void gemm_fused(const void* __restrict__ Aptr,
        const unsigned short* __restrict__ WT,
        const float* __restrict__ att_s, const float* __restrict__ att_d,
        unsigned short* __restrict__ outh,
        float* __restrict__ a_src, float* __restrict__ a_dst) {
    constexpr int WN  = NC / 4;
    constexpr int NT  = WN / 16;
    constexpr int TPH = C / 16;
    constexpr int BJ  = NC / 32;
    __shared__ unsigned short As[64 * 64];
    __shared__ unsigned short Bs[NC * 64];
    const int m0 = blockIdx.x * 64;
    const int tid  = threadIdx.x;
    const int wave = tid >> 6, lane = tid & 63;
    const int col = lane & 15, quad = lane >> 4;
    const int ar = tid >> 2;
    const int ac = tid & 3;
    const int arow = min(m0 + ar, N_NODES - 1);   // guard input read

    f32x4 acc[4][NT] = {};

    for (int k0 = 0; k0 < 256; k0 += 64) {
        u16x8 av[2];
        if constexpr (AF32) {
            const float* Af = (const float*)Aptr;
#pragma unroll
            for (int j = 0; j < 2; j++) {
                const float* p = Af + (size_t)arow * 256 + k0 + (ac + j * 4) * 8;
                float4 f0 = *(const float4*)p;
                float4 f1 = *(const float4*)(p + 4);
                u16x8 v;
                v[0] = f2bf(f0.x); v[1] = f2bf(f0.y); v[2] = f2bf(f0.z); v[3] = f2bf(f0.w);
                v[4] = f2bf(f1.x); v[5] = f2bf(f1.y); v[6] = f2bf(f1.z); v[7] = f2bf(f1.w);
                av[j] = v;
            }
        } else {
            const unsigned short* Ab = (const unsigned short*)Aptr;
#pragma unroll
            for (int j = 0; j < 2; j++)
                av[j] = *(const u16x8*)(Ab + (size_t)arow * 256 + k0 + (ac + j * 4) * 8);
        }
        u16x8 bv[BJ];
#pragma unroll
        for (int j = 0; j < BJ; j++) {
            int idx = j * 256 + tid, row = idx >> 3, ch = idx & 7;
            bv[j] = *(const u16x8*)(WT + (size_t)row * 256 + k0 + ch * 8);
        }
        __syncthreads();
#pragma unroll
        for (int j = 0; j < 2; j++) {
            int ch = ac + j * 4;
            *(u16x8*)&As[ar * 64 + (ch ^ (ar & 7)) * 8] = av[j];
        }
#pragma unroll
        for (int j = 0; j < BJ; j++) {
            int idx = j * 256 + tid, row = idx >> 3, ch = idx & 7;
            *(u16x8*)&Bs[row * 64 + (ch ^ (row & 7)) * 8] = bv[j];
        }
        __syncthreads();
#pragma unroll
        for (int ks = 0; ks < 64; ks += 32) {
            bf16x8 af[4], bfm[NT];
#pragma unroll
            for (int mi = 0; mi < 4; mi++) {
                int r = mi * 16 + col, c = (ks >> 3) + quad;
                af[mi] = *(const bf16x8*)&As[r * 64 + (c ^ (r & 7)) * 8];
            }
#pragma unroll
            for (int ni = 0; ni < NT; ni++) {
                int r = wave * WN + ni * 16 + col, c = (ks >> 3) + quad;
                bfm[ni] = *(const bf16x8*)&Bs[r * 64 + (c ^ (r & 7)) * 8];
            }
#pragma unroll
            for (int mi = 0; mi < 4; mi++)
#pragma unroll
                for (int ni = 0; ni < NT; ni++)
                    acc[mi][ni] = __builtin_amdgcn_mfma_f32_16x16x32_bf16(
                        af[mi], bfm[ni], acc[mi][ni], 0, 0, 0);
        }
    }

#pragma unroll
    for (int mi = 0; mi < 4; mi++)
#pragma unroll
        for (int ni = 0; ni < NT; ni++)
#pragma unroll
            for (int r = 0; r < 4; r++) {
                int m = m0 + mi * 16 + quad * 4 + r;
                if (m < N_NODES)
                    outh[(size_t)m * NC + wave * WN + ni * 16 + col] = f2bf(acc[mi][ni][r]);
            }

    float asv[NT], adv[NT];
#pragma unroll
    for (int ni = 0; ni < NT; ni++) {
        int n = wave * WN + ni * 16 + col;
        asv[ni] = att_s[n];
        adv[ni] = att_d[n];
    }
#pragma unroll
    for (int mi = 0; mi < 4; mi++)
#pragma unroll
        for (int r = 0; r < 4; r++) {
#pragma unroll
            for (int hl = 0; hl < 2; hl++) {
                float s = 0.f, d = 0.f;
#pragma unroll
                for (int t = 0; t < TPH; t++) {
                    int ni = hl * TPH + t;
                    s = fmaf(acc[mi][ni][r], asv[ni], s);
                    d = fmaf(acc[mi][ni][r], adv[ni], d);
                }
#pragma unroll
                for (int off = 1; off < 16; off <<= 1) {
                    s += __shfl_xor(s, off);
                    d += __shfl_xor(d, off);
                }
                if (col == 0) {
                    int m = m0 + mi * 16 + quad * 4 + r;
                    if (m < N_NODES) {
                        int hh = wave * 2 + hl;
                        a_src[m * 8 + hh] = s;
                        a_dst[m * 8 + hh] = d;
                    }
                }
            }
        }
}

// ---- layer-1 aggregation: ONE WAVE per node, half-wave edge pairing -----
// R7-proven config: 4 pairs (8 edges) per iteration; lane q covers feats
// [q*8,q*8+8) of head q>>2 (16 B dwordx4 gather; 32 lanes = 512 B row).
// No max-subtraction (|e| small analytically -> exp safe in fp32).

__global__ __launch_bounds__(256) void gat_agg_l1(const int* __restrict__ row_start,
        const unsigned short* __restrict__ csr,
        const unsigned short* __restrict__ hfeat, const float* __restrict__ a_src,
        const float* __restrict__ a_dst, const float* __restrict__ bias,
        unsigned short* __restrict__ outp) {
    const int n    = blockIdx.x * 4 + (threadIdx.x >> 6);
    const int lane = threadIdx.x & 63;
    if (n >= N_NODES) return;

    const int rs  = row_start[n];
    const int deg = row_start[n + 1] - rs;
    const int p   = lane >> 5;          // edge parity
    const int q   = lane & 31;          // feat group
    const int hq  = q >> 2;             // head
    const float adstf = a_dst[n * 8 + hq];

    float acc[8] = {};
    float den = 0.f;

    for (int c0 = 0; c0 < deg; c0 += 64) {
        const int cnt = min(64, deg - c0);
        int myid = (lane < cnt) ? (int)csr[rs + c0 + lane] : 0;
        int e = 0;
        for (; e + 8 <= cnt; e += 8) {          // 4 pairs = 8 edges
            int ss[4];
#pragma unroll
            for (int j = 0; j < 4; j++) ss[j] = __shfl(myid, e + j * 2 + p);
            float as[4];
#pragma unroll
            for (int j = 0; j < 4; j++) as[j] = a_src[ss[j] * 8 + hq];
            u16x8 v[4];
#pragma unroll
            for (int j = 0; j < 4; j++)
                v[j] = *(const u16x8*)(hfeat + (size_t)ss[j] * 256 + q * 8);
#pragma unroll
            for (int j = 0; j < 4; j++) {
                float w = __expf(lrelu(as[j] + adstf));
                den += w;
#pragma unroll
                for (int k = 0; k < 8; k++)
                    acc[k] = fmaf(w, bf2f(v[j][k]), acc[k]);
            }
        }
        for (; e < cnt; e += 2) {               // tail pairs
            int idx = e + p;
            bool ok = idx < cnt;
            int s = __shfl(myid, ok ? idx : cnt - 1);
            float w = ok ? __expf(lrelu(a_src[s * 8 + hq] + adstf)) : 0.f;
            den += w;
            u16x8 v = *(const u16x8*)(hfeat + (size_t)s * 256 + q * 8);
#pragma unroll
            for (int k = 0; k < 8; k++)
                acc[k] = fmaf(w, bf2f(v[k]), acc[k]);
        }
    }

    // combine parities
    den += __shfl_xor(den, 32);
#pragma unroll
    for (int k = 0; k < 8; k++) acc[k] += __shfl_xor(acc[k], 32);

    if (p == 0) {
        const float inv = 1.f / (den + 1e-16f);
        float4 b0 = *(const float4*)(bias + q * 8);
        float4 b1 = *(const float4*)(bias + q * 8 + 4);
        float bb[8] = {b0.x, b0.y, b0.z, b0.w, b1.x, b1.y, b1.z, b1.w};
        u16x8 o;
#pragma unroll
        for (int k = 0; k < 8; k++) {
            float v = acc[k] * inv + bb[k];
            o[k] = f2bf(v > 0.f ? v : __expf(v) - 1.f);   // elu
        }
        *(u16x8*)(outp + (size_t)n * 256 + q * 8) = o;
    }
}

// ---- layer-2 aggregation: ONE WAVE per node (R7-proven, F=128) ----------

__global__ __launch_bounds__(256) void gat_agg_l2(const int* __restrict__ row_start,
        const unsigned short* __restrict__ csr,
        const unsigned short* __restrict__ hfeat, const float* __restrict__ a_src,
        const float* __restrict__ a_dst, const float* __restrict__ bias,
        float* __restrict__ outp) {
    const int n    = blockIdx.x * 4 + (threadIdx.x >> 6);
    const int lane = threadIdx.x & 63;
    if (n >= N_NODES) return;

    const int rs  = row_start[n];
    const int deg = row_start[n + 1] - rs;
    const int hf  = lane >> 3;
    const float adstf = a_dst[n * 8 + hf];

    float acc0 = 0.f, acc1 = 0.f, den = 0.f;

    for (int c0 = 0; c0 < deg; c0 += 64) {
        const int cnt = min(64, deg - c0);
        int myid = (lane < cnt) ? (int)csr[rs + c0 + lane] : 0;
        int e = 0;
        for (; e + 8 <= cnt; e += 8) {
            int ss[8];
#pragma unroll
            for (int j = 0; j < 8; j++) ss[j] = __shfl(myid, e + j);
            float as[8];
#pragma unroll
            for (int j = 0; j < 8; j++) as[j] = a_src[ss[j] * 8 + hf];
            ushort2 v[8];
#pragma unroll
            for (int j = 0; j < 8; j++)
                v[j] = *(const ushort2*)(hfeat + (size_t)ss[j] * 128 + lane * 2);
#pragma unroll
            for (int j = 0; j < 8; j++) {
                float w = __expf(lrelu(as[j] + adstf));
                den += w;
                acc0 = fmaf(w, bf2f(v[j].x), acc0);
                acc1 = fmaf(w, bf2f(v[j].y), acc1);
            }
        }
        for (; e < cnt; e++) {
            int s = __shfl(myid, e);
            float w = __expf(lrelu(a_src[s * 8 + hf] + adstf));
            den += w;
            ushort2 hv = *(const ushort2*)(hfeat + (size_t)s * 128 + lane * 2);
            acc0 = fmaf(w, bf2f(hv.x), acc0);
            acc1 = fmaf(w, bf2f(hv.y), acc1);
        }
    }

    const float inv = 1.f / (den + 1e-16f);
    float a0 = acc0 * inv, a1 = acc1 * inv;
#pragma unroll
    for (int off = 8; off <= 32; off <<= 1) {
        a0 += __shfl_xor(a0, off);
        a1 += __shfl_xor(a1, off);
    }
    if (lane < 8) {
        float2 o;
        o.x = a0 * 0.125f + bias[lane * 2 + 0];
        o.y = a1 * 0.125f + bias[lane * 2 + 1];
        *(float2*)(outp + (size_t)n * 16 + lane * 2) = o;
    }
}

// ---- host ---------------------------------------------------------------

extern "C" void kernel_launch(void* const* d_in, const int* in_sizes, int n_in,
                              void* d_out, int out_size, void* d_ws, size_t ws_size,
                              hipStream_t stream) {
    const float* x        = (const float*)d_in[0];
    const int*   ei       = (const int*)d_in[1];
    const float* W1       = (const float*)d_in[2];
    const float* att_src1 = (const float*)d_in[3];
    const float* att_dst1 = (const float*)d_in[4];
    const float* bias1    = (const float*)d_in[5];
    const float* W2       = (const float*)d_in[6];
    const float* att_src2 = (const float*)d_in[7];
    const float* att_dst2 = (const float*)d_in[8];
    const float* bias2    = (const float*)d_in[9];
    float* out = (float*)d_out;

    char* ws = (char*)d_ws;
    unsigned short* h1  = (unsigned short*)(ws);                       // bf16 [N,256]
    unsigned short* h2  = (unsigned short*)(ws);                       // bf16 [N,128] overlays
    unsigned short* x2b = (unsigned short*)(ws + 32ull * 1024 * 1024); // bf16 [N,256]
    unsigned short* W1T = (unsigned short*)(ws + 64ull * 1024 * 1024); // bf16 [256,256]
    unsigned short* W2T = W1T + 65536;                                 // bf16 [128,256]
    char* aux = ws + 66ull * 1024 * 1024;
    float*          a_src     = (float*)(aux);                         // [N,8]
    float*          a_dst     = (float*)(aux + 1600000);               // [N,8]
    int*            row_start = (int*)  (aux + 3200000);               // [N+1]
    int*            cnt       = (int*)  (aux + 3400064);               // [N] -> cursor
    unsigned short* csr       = (unsigned short*)(aux + 3600128);      // [EP]
    int*            incl      = (int*)  (aux + 5300128);               // [50176]
    int*            bsum      = (int*)  (aux + 5500832);               // [196]

    const int MT = (N_NODES + 63) / 64;            // 782
    const int AGG_BLOCKS = (N_NODES + 3) / 4;

    // ---- CSR build + W prep ----
    hipMemsetAsync(cnt, 0, N_NODES * sizeof(int), stream);
    hist_prep<<<E_BLOCKS + W_BLOCKS, 256, 0, stream>>>(ei, cnt, W1, W2, W1T, W2T);
    scan_p1<<<SCAN_BLOCKS, 256, 0, stream>>>(cnt, incl, bsum);
    scan_p23<<<SCAN_BLOCKS, 256, 0, stream>>>(incl, bsum, cnt, row_start);
    fill_kernel<<<E_BLOCKS, 256, 0, stream>>>(ei, cnt, csr);

    // ---- layer 1 (GEMM reads fp32 x directly) ----
    gemm_fused<256, 32, true><<<MT, 256, 0, stream>>>(x, W1T, att_src1, att_dst1, h1, a_src, a_dst);
    gat_agg_l1<<<AGG_BLOCKS, 256, 0, stream>>>(row_start, csr, h1, a_src, a_dst, bias1, x2b);

    // ---- layer 2 ----
    gemm_fused<128, 16, false><<<MT, 256, 0, stream>>>(x2b, W2T, att_src2, att_dst2, h2, a_src, a_dst);
    gat_agg_l2<<<AGG_BLOCKS, 256, 0, stream>>>(row_start, csr, h2, a_src, a_dst, bias2, out);
}

// Round 11
// 333.535 us; speedup vs baseline: 1.1205x; 1.0128x over previous
//
#include <hip/hip_runtime.h>

#define N_NODES 50000
#define N_EDGES 800000
#define EP (N_EDGES + N_NODES)   /* 850000 edges incl. self loops */
#define HEADS 8
#define NEG 0.2f

typedef __attribute__((ext_vector_type(8))) short bf16x8;
typedef __attribute__((ext_vector_type(8))) unsigned short u16x8;
typedef __attribute__((ext_vector_type(4))) float f32x4;

#define E_BLOCKS ((EP + 255) / 256)        /* 3321 */
#define MT_BLOCKS ((N_NODES + 63) / 64)    /* 782 */
#define SCAN_BLOCKS 196                    /* 196*256 = 50176 >= N_NODES */
#define W_ITEMS  (65536 + 32768)
#define W_BLOCKS ((W_ITEMS + 255) / 256)   /* 384 */

// ---- bf16 helpers (storage compression; math stays fp32) ----------------

__device__ __forceinline__ float bf2f(unsigned short u) {
    return __uint_as_float(((unsigned)u) << 16);
}
__device__ __forceinline__ unsigned short f2bf(float f) {
    unsigned u = __float_as_uint(f);
    return (unsigned short)((u + 0x7FFFu + ((u >> 16) & 1u)) >> 16);  // RNE
}

__device__ __forceinline__ void get_edge(const int* __restrict__ ei, int e, int& s, int& d) {
    if (e < N_EDGES) { s = ei[e]; d = ei[N_EDGES + e]; }
    else             { s = d = e - N_EDGES; }           // self loop
}

__device__ __forceinline__ float lrelu(float v) { return v > 0.f ? v : NEG * v; }

// ---- phase 0: zero cnt + W1/W2 -> bf16 transposed [n][k] ----------------

__global__ void zero_wprep(int* __restrict__ cnt,
                           const float* __restrict__ W1, const float* __restrict__ W2,
                           unsigned short* __restrict__ W1T, unsigned short* __restrict__ W2T) {
    const int b = blockIdx.x;
    if (b < SCAN_BLOCKS) {
        int idx = b * 256 + threadIdx.x;
        if (idx < N_NODES) cnt[idx] = 0;
    } else {
        int t = (b - SCAN_BLOCKS) * 256 + threadIdx.x;
        if (t < 65536) {
            int k = t >> 8, n = t & 255;
            W1T[n * 256 + k] = f2bf(W1[k * 256 + n]);
        } else if (t < W_ITEMS) {
            int u = t - 65536; int k = u >> 7, n = u & 127;
            W2T[n * 256 + k] = f2bf(W2[k * 128 + n]);
        }
    }
}

// ---- phase 1: histogram of in-degrees -----------------------------------

__global__ void hist_kernel(const int* __restrict__ ei, int* __restrict__ cnt) {
    int e = blockIdx.x * 256 + threadIdx.x;
    if (e >= EP) return;
    int s, d; get_edge(ei, e, s, d);
    atomicAdd(&cnt[d], 1);
}

// ---- 2-phase parallel exclusive scan ------------------------------------

__global__ __launch_bounds__(256) void scan_p1(const int* __restrict__ cnt,
                                               int* __restrict__ incl, int* __restrict__ bsum) {
    __shared__ int wsum[4];
    const int tid = threadIdx.x, lane = tid & 63, wid = tid >> 6;
    const int idx = blockIdx.x * 256 + tid;
    int v = (idx < N_NODES) ? cnt[idx] : 0;
#pragma unroll
    for (int off = 1; off < 64; off <<= 1) {
        int t = __shfl_up(v, off);
        if (lane >= off) v += t;
    }
    if (lane == 63) wsum[wid] = v;
    __syncthreads();
    int add = 0;
#pragma unroll
    for (int w = 0; w < 4; w++) add += (w < wid) ? wsum[w] : 0;
    incl[idx] = v + add;
    if (tid == 255) bsum[blockIdx.x] = v + add;
}

__global__ __launch_bounds__(256) void scan_p23(const int* __restrict__ incl,
                                                const int* __restrict__ bsum,
                                                int* __restrict__ cnt_cursor,
                                                int* __restrict__ row_start) {
    __shared__ int sb[256];
    __shared__ int wsum[4];
    const int tid = threadIdx.x, lane = tid & 63, wid = tid >> 6;
    int v = (tid < SCAN_BLOCKS) ? bsum[tid] : 0;
#pragma unroll
    for (int off = 1; off < 64; off <<= 1) {
        int t = __shfl_up(v, off);
        if (lane >= off) v += t;
    }
    if (lane == 63) wsum[wid] = v;
    __syncthreads();
    int add = 0;
#pragma unroll
    for (int w = 0; w < 4; w++) add += (w < wid) ? wsum[w] : 0;
    sb[tid] = v + add;                     // inclusive scan of bsum
    __syncthreads();
    const int bex = (blockIdx.x == 0) ? 0 : sb[blockIdx.x - 1];
    const int idx = blockIdx.x * 256 + tid;
    if (idx == 0) row_start[N_NODES] = EP;
    if (idx >= N_NODES) return;
    int ex = bex + incl[idx] - cnt_cursor[idx];
    row_start[idx] = ex;
    cnt_cursor[idx] = ex;
}

// ---- MFMA GEMM body, A read ONCE (BM=64 x full-N) + fused att epilogue --

template<int NC, int C, bool AF32>
__device__ __forceinline__ void gemm_body(int bx, const void* __restrict__ Aptr,
        const unsigned short* __restrict__ WT,
        const float* __restrict__ att_s, const float* __restrict__ att_d,
        unsigned short* __restrict__ outh,
        float* __restrict__ a_src, float* __restrict__ a_dst) {
    constexpr int WN  = NC / 4;
    constexpr int NT  = WN / 16;
    constexpr int TPH = C / 16;
    constexpr int BJ  = NC / 32;
    __shared__ unsigned short As[64 * 64];
    __shared__ unsigned short Bs[NC * 64];
    const int m0 = bx * 64;
    const int tid  = threadIdx.x;
    const int wave = tid >> 6, lane = tid & 63;
    const int col = lane & 15, quad = lane >> 4;
    const int ar = tid >> 2;
    const int ac = tid & 3;
    const int arow = min(m0 + ar, N_NODES - 1);   // guard input read

    f32x4 acc[4][NT] = {};

    for (int k0 = 0; k0 < 256; k0 += 64) {
        u16x8 av[2];
        if constexpr (AF32) {
            const float* Af = (const float*)Aptr;
#pragma unroll
            for (int j = 0; j < 2; j++) {
                const float* p = Af + (size_t)arow * 256 + k0 + (ac + j * 4) * 8;
                float4 f0 = *(const float4*)p;
                float4 f1 = *(const float4*)(p + 4);
                u16x8 v;
                v[0] = f2bf(f0.x); v[1] = f2bf(f0.y); v[2] = f2bf(f0.z); v[3] = f2bf(f0.w);
                v[4] = f2bf(f1.x); v[5] = f2bf(f1.y); v[6] = f2bf(f1.z); v[7] = f2bf(f1.w);
                av[j] = v;
            }
        } else {
            const unsigned short* Ab = (const unsigned short*)Aptr;
#pragma unroll
            for (int j = 0; j < 2; j++)
                av[j] = *(const u16x8*)(Ab + (size_t)arow * 256 + k0 + (ac + j * 4) * 8);
        }
        u16x8 bv[BJ];
#pragma unroll
        for (int j = 0; j < BJ; j++) {
            int idx = j * 256 + tid, row = idx >> 3, ch = idx & 7;
            bv[j] = *(const u16x8*)(WT + (size_t)row * 256 + k0 + ch * 8);
        }
        __syncthreads();
#pragma unroll
        for (int j = 0; j < 2; j++) {
            int ch = ac + j * 4;
            *(u16x8*)&As[ar * 64 + (ch ^ (ar & 7)) * 8] = av[j];
        }
#pragma unroll
        for (int j = 0; j < BJ; j++) {
            int idx = j * 256 + tid, row = idx >> 3, ch = idx & 7;
            *(u16x8*)&Bs[row * 64 + (ch ^ (row & 7)) * 8] = bv[j];
        }
        __syncthreads();
#pragma unroll
        for (int ks = 0; ks < 64; ks += 32) {
            bf16x8 af[4], bfm[NT];
#pragma unroll
            for (int mi = 0; mi < 4; mi++) {
                int r = mi * 16 + col, c = (ks >> 3) + quad;
                af[mi] = *(const bf16x8*)&As[r * 64 + (c ^ (r & 7)) * 8];
            }
#pragma unroll
            for (int ni = 0; ni < NT; ni++) {
                int r = wave * WN + ni * 16 + col, c = (ks >> 3) + quad;
                bfm[ni] = *(const bf16x8*)&Bs[r * 64 + (c ^ (r & 7)) * 8];
            }
#pragma unroll
            for (int mi = 0; mi < 4; mi++)
#pragma unroll
                for (int ni = 0; ni < NT; ni++)
                    acc[mi][ni] = __builtin_amdgcn_mfma_f32_16x16x32_bf16(
                        af[mi], bfm[ni], acc[mi][ni], 0, 0, 0);
        }
    }

#pragma unroll
    for (int mi = 0; mi < 4; mi++)
#pragma unroll
        for (int ni = 0; ni < NT; ni++)
#pragma unroll
            for (int r = 0; r < 4; r++) {
                int m = m0 + mi * 16 + quad * 4 + r;
                if (m < N_NODES)
                    outh[(size_t)m * NC + wave * WN + ni * 16 + col] = f2bf(acc[mi][ni][r]);
            }

    float asv[NT], adv[NT];
#pragma unroll
    for (int ni = 0; ni < NT; ni++) {
        int n = wave * WN + ni * 16 + col;
        asv[ni] = att_s[n];
        adv[ni] = att_d[n];
    }
#pragma unroll
    for (int mi = 0; mi < 4; mi++)
#pragma unroll
        for (int r = 0; r < 4; r++) {
#pragma unroll
            for (int hl = 0; hl < 2; hl++) {
                float s = 0.f, d = 0.f;
#pragma unroll
                for (int t = 0; t < TPH; t++) {
                    int ni = hl * TPH + t;
                    s = fmaf(acc[mi][ni][r], asv[ni], s);
                    d = fmaf(acc[mi][ni][r], adv[ni], d);
                }
#pragma unroll
                for (int off = 1; off < 16; off <<= 1) {
                    s += __shfl_xor(s, off);
                    d += __shfl_xor(d, off);
                }
                if (col == 0) {
                    int m = m0 + mi * 16 + quad * 4 + r;
                    if (m < N_NODES) {
                        int hh = wave * 2 + hl;
                        a_src[m * 8 + hh] = s;
                        a_dst[m * 8 + hh] = d;
                    }
                }
            }
        }
}

// ---- merged: gemm layer-1 (blocks 0..MT) + CSR fill (blocks MT..) -------
// Independent work: gemm is MFMA/LDS-bound, fill is atomic-bound; running
// them in one dispatch overlaps fill behind gemm (time ~ max, not sum).

__global__ __launch_bounds__(256) void gemm1_fill(const float* __restrict__ x,
        const unsigned short* __restrict__ W1T,
        const float* __restrict__ att_s, const float* __restrict__ att_d,
        unsigned short* __restrict__ outh,
        float* __restrict__ a_src, float* __restrict__ a_dst,
        const int* __restrict__ ei, int* __restrict__ cursor,
        unsigned short* __restrict__ csr) {
    if (blockIdx.x < MT_BLOCKS) {
        gemm_body<256, 32, true>(blockIdx.x, x, W1T, att_s, att_d, outh, a_src, a_dst);
    } else {
        int e = (blockIdx.x - MT_BLOCKS) * 256 + threadIdx.x;
        if (e >= EP) return;
        int s, d; get_edge(ei, e, s, d);
        int pos = atomicAdd(&cursor[d], 1);
        csr[pos] = (unsigned short)s;
    }
}

__global__ __launch_bounds__(256) void gemm2_kernel(const unsigned short* __restrict__ x2b,
        const unsigned short* __restrict__ W2T,
        const float* __restrict__ att_s, const float* __restrict__ att_d,
        unsigned short* __restrict__ outh,
        float* __restrict__ a_src, float* __restrict__ a_dst) {
    gemm_body<128, 16, false>(blockIdx.x, x2b, W2T, att_s, att_d, outh, a_src, a_dst);
}

// ---- layer-1 aggregation: ONE WAVE per node, half-wave edge pairing -----
// R7-proven config: 4 pairs (8 edges) per iteration; lane q covers feats
// [q*8,q*8+8) of head q>>2 (16 B dwordx4 gather; 32 lanes = 512 B row).
// No max-subtraction (|e| small analytically -> exp safe in fp32).

__global__ __launch_bounds__(256) void gat_agg_l1(const int* __restrict__ row_start,
        const unsigned short* __restrict__ csr,
        const unsigned short* __restrict__ hfeat, const float* __restrict__ a_src,
        const float* __restrict__ a_dst, const float* __restrict__ bias,
        unsigned short* __restrict__ outp) {
    const int n    = blockIdx.x * 4 + (threadIdx.x >> 6);
    const int lane = threadIdx.x & 63;
    if (n >= N_NODES) return;

    const int rs  = row_start[n];
    const int deg = row_start[n + 1] - rs;
    const int p   = lane >> 5;          // edge parity
    const int q   = lane & 31;          // feat group
    const int hq  = q >> 2;             // head
    const float adstf = a_dst[n * 8 + hq];

    float acc[8] = {};
    float den = 0.f;

    for (int c0 = 0; c0 < deg; c0 += 64) {
        const int cnt = min(64, deg - c0);
        int myid = (lane < cnt) ? (int)csr[rs + c0 + lane] : 0;
        int e = 0;
        for (; e + 8 <= cnt; e += 8) {          // 4 pairs = 8 edges
            int ss[4];
#pragma unroll
            for (int j = 0; j < 4; j++) ss[j] = __shfl(myid, e + j * 2 + p);
            float as[4];
#pragma unroll
            for (int j = 0; j < 4; j++) as[j] = a_src[ss[j] * 8 + hq];
            u16x8 v[4];
#pragma unroll
            for (int j = 0; j < 4; j++)
                v[j] = *(const u16x8*)(hfeat + (size_t)ss[j] * 256 + q * 8);
#pragma unroll
            for (int j = 0; j < 4; j++) {
                float w = __expf(lrelu(as[j] + adstf));
                den += w;
#pragma unroll
                for (int k = 0; k < 8; k++)
                    acc[k] = fmaf(w, bf2f(v[j][k]), acc[k]);
            }
        }
        for (; e < cnt; e += 2) {               // tail pairs
            int idx = e + p;
            bool ok = idx < cnt;
            int s = __shfl(myid, ok ? idx : cnt - 1);
            float w = ok ? __expf(lrelu(a_src[s * 8 + hq] + adstf)) : 0.f;
            den += w;
            u16x8 v = *(const u16x8*)(hfeat + (size_t)s * 256 + q * 8);
#pragma unroll
            for (int k = 0; k < 8; k++)
                acc[k] = fmaf(w, bf2f(v[k]), acc[k]);
        }
    }

    // combine parities
    den += __shfl_xor(den, 32);
#pragma unroll
    for (int k = 0; k < 8; k++) acc[k] += __shfl_xor(acc[k], 32);

    if (p == 0) {
        const float inv = 1.f / (den + 1e-16f);
        float4 b0 = *(const float4*)(bias + q * 8);
        float4 b1 = *(const float4*)(bias + q * 8 + 4);
        float bb[8] = {b0.x, b0.y, b0.z, b0.w, b1.x, b1.y, b1.z, b1.w};
        u16x8 o;
#pragma unroll
        for (int k = 0; k < 8; k++) {
            float v = acc[k] * inv + bb[k];
            o[k] = f2bf(v > 0.f ? v : __expf(v) - 1.f);   // elu
        }
        *(u16x8*)(outp + (size_t)n * 256 + q * 8) = o;
    }
}

// ---- layer-2 aggregation: ONE WAVE per node (R7-proven, F=128) ----------

__global__ __launch_bounds__(256) void gat_agg_l2(const int* __restrict__ row_start,
        const unsigned short* __restrict__ csr,
        const unsigned short* __restrict__ hfeat, const float* __restrict__ a_src,
        const float* __restrict__ a_dst, const float* __restrict__ bias,
        float* __restrict__ outp) {
    const int n    = blockIdx.x * 4 + (threadIdx.x >> 6);
    const int lane = threadIdx.x & 63;
    if (n >= N_NODES) return;

    const int rs  = row_start[n];
    const int deg = row_start[n + 1] - rs;
    const int hf  = lane >> 3;
    const float adstf = a_dst[n * 8 + hf];

    float acc0 = 0.f, acc1 = 0.f, den = 0.f;

    for (int c0 = 0; c0 < deg; c0 += 64) {
        const int cnt = min(64, deg - c0);
        int myid = (lane < cnt) ? (int)csr[rs + c0 + lane] : 0;
        int e = 0;
        for (; e + 8 <= cnt; e += 8) {
            int ss[8];
#pragma unroll
            for (int j = 0; j < 8; j++) ss[j] = __shfl(myid, e + j);
            float as[8];
#pragma unroll
            for (int j = 0; j < 8; j++) as[j] = a_src[ss[j] * 8 + hf];
            ushort2 v[8];
#pragma unroll
            for (int j = 0; j < 8; j++)
                v[j] = *(const ushort2*)(hfeat + (size_t)ss[j] * 128 + lane * 2);
#pragma unroll
            for (int j = 0; j < 8; j++) {
                float w = __expf(lrelu(as[j] + adstf));
                den += w;
                acc0 = fmaf(w, bf2f(v[j].x), acc0);
                acc1 = fmaf(w, bf2f(v[j].y), acc1);
            }
        }
        for (; e < cnt; e++) {
            int s = __shfl(myid, e);
            float w = __expf(lrelu(a_src[s * 8 + hf] + adstf));
            den += w;
            ushort2 hv = *(const ushort2*)(hfeat + (size_t)s * 128 + lane * 2);
            acc0 = fmaf(w, bf2f(hv.x), acc0);
            acc1 = fmaf(w, bf2f(hv.y), acc1);
        }
    }

    const float inv = 1.f / (den + 1e-16f);
    float a0 = acc0 * inv, a1 = acc1 * inv;
#pragma unroll
    for (int off = 8; off <= 32; off <<= 1) {
        a0 += __shfl_xor(a0, off);
        a1 += __shfl_xor(a1, off);
    }
    if (lane < 8) {
        float2 o;
        o.x = a0 * 0.125f + bias[lane * 2 + 0];
        o.y = a1 * 0.125f + bias[lane * 2 + 1];
        *(float2*)(outp + (size_t)n * 16 + lane * 2) = o;
    }
}

// ---- host ---------------------------------------------------------------

extern "C" void kernel_launch(void* const* d_in, const int* in_sizes, int n_in,
                              void* d_out, int out_size, void* d_ws, size_t ws_size,
                              hipStream_t stream) {
    const float* x        = (const float*)d_in[0];
    const int*   ei       = (const int*)d_in[1];
    const float* W1       = (const float*)d_in[2];
    const float* att_src1 = (const float*)d_in[3];
    const float* att_dst1 = (const float*)d_in[4];
    const float* bias1    = (const float*)d_in[5];
    const float* W2       = (const float*)d_in[6];
    const float* att_src2 = (const float*)d_in[7];
    const float* att_dst2 = (const float*)d_in[8];
    const float* bias2    = (const float*)d_in[9];
    float* out = (float*)d_out;

    char* ws = (char*)d_ws;
    unsigned short* h1  = (unsigned short*)(ws);                       // bf16 [N,256]
    unsigned short* h2  = (unsigned short*)(ws);                       // bf16 [N,128] overlays
    unsigned short* x2b = (unsigned short*)(ws + 32ull * 1024 * 1024); // bf16 [N,256]
    unsigned short* W1T = (unsigned short*)(ws + 64ull * 1024 * 1024); // bf16 [256,256]
    unsigned short* W2T = W1T + 65536;                                 // bf16 [128,256]
    char* aux = ws + 66ull * 1024 * 1024;
    float*          a_src     = (float*)(aux);                         // [N,8]
    float*          a_dst     = (float*)(aux + 1600000);               // [N,8]
    int*            row_start = (int*)  (aux + 3200000);               // [N+1]
    int*            cnt       = (int*)  (aux + 3400064);               // [N] -> cursor
    unsigned short* csr       = (unsigned short*)(aux + 3600128);      // [EP]
    int*            incl      = (int*)  (aux + 5300128);               // [50176]
    int*            bsum      = (int*)  (aux + 5500832);               // [196]

    const int AGG_BLOCKS = (N_NODES + 3) / 4;

    // ---- phase 0/1: zero+Wprep, then degree histogram ----
    zero_wprep<<<SCAN_BLOCKS + W_BLOCKS, 256, 0, stream>>>(cnt, W1, W2, W1T, W2T);
    hist_kernel<<<E_BLOCKS, 256, 0, stream>>>(ei, cnt);
    scan_p1<<<SCAN_BLOCKS, 256, 0, stream>>>(cnt, incl, bsum);
    scan_p23<<<SCAN_BLOCKS, 256, 0, stream>>>(incl, bsum, cnt, row_start);

    // ---- layer 1: gemm (reads fp32 x) + CSR fill merged in one dispatch ----
    gemm1_fill<<<MT_BLOCKS + E_BLOCKS, 256, 0, stream>>>(x, W1T, att_src1, att_dst1,
                                                         h1, a_src, a_dst, ei, cnt, csr);
    gat_agg_l1<<<AGG_BLOCKS, 256, 0, stream>>>(row_start, csr, h1, a_src, a_dst, bias1, x2b);

    // ---- layer 2 ----
    gemm2_kernel<<<MT_BLOCKS, 256, 0, stream>>>(x2b, W2T, att_src2, att_dst2, h2, a_src, a_dst);
    gat_agg_l2<<<AGG_BLOCKS, 256, 0, stream>>>(row_start, csr, h2, a_src, a_dst, bias2, out);
}